// Round 13
// baseline (143.169 us; speedup 1.0000x reference)
//
#include <hip/hip_runtime.h>
#include <hip/hip_bf16.h>

// BehaviorSpecificPFF: grouped-GEMM implementation, round 13.
// Change vs round 12: DENSE GEMM GRID. The old grid launched (NTOK/128) row
// tiles per behavior and early-exited rt >= rows_padded; active blocks were
// those with (dispatch mod 128) < ~26, which round-robin dispatch piles onto
// ~52 of 256 CUs -> 80% of the chip idle (the measured Occupancy 14% and the
// schedule-invariant MfmaUtil 20% plateau). Now blockIdx.x is a GLOBAL
// compacted row-tile (0..131); behavior is looked up from hdr; virtually all
// launched blocks do real work, spread over all CUs.
// GEMM core (BK=64 128^2, coalesced+XOR-swizzled staging, 2-deep counted
// vmcnt, 0 conflicts) is round-12 verbatim.

#define NTOK 16384   // B*T = 8*2048
#define DM   512     // d_model
#define DF   2048    // d_ff
#define NB   4       // behaviors (excluding padding class 0)
#define MAXR (NTOK + 512)
#define MAXRT 132    // worst-case padded row-tiles: NTOK/128 + NB

typedef __attribute__((ext_vector_type(8))) short bf16x8;
typedef __attribute__((ext_vector_type(4))) float f32x4;
typedef __attribute__((ext_vector_type(4))) unsigned short u16x4;
typedef __attribute__((ext_vector_type(8))) unsigned short u16x8;

__device__ inline unsigned short f2bf(float f) {
  union { float f; unsigned u; } x; x.f = f;
  unsigned r = x.u + 0x7fffu + ((x.u >> 16) & 1u);   // RNE
  return (unsigned short)(r >> 16);
}
__device__ inline float bf2f(unsigned short h) {
  union { unsigned u; float f; } x; x.u = ((unsigned)h) << 16; return x.f;
}
__device__ inline void gload16(const void* g, void* l) {
  __builtin_amdgcn_global_load_lds(
      (const __attribute__((address_space(1))) unsigned int*)g,
      (__attribute__((address_space(3))) unsigned int*)l, 16, 0, 0);
}

// ---------------------------------------------------------------------------
// Header layout in ws (uint32): [0..3]=cnt[4], [4..7]=segoff[4] (row offsets,
// 128-aligned segments), [8..11]=segpad[4], [12]=total_padded
// ---------------------------------------------------------------------------

// Single-block ordered compaction: 1024 threads x 16 tokens each.
__global__ __launch_bounds__(1024) void k_scan(const int* __restrict__ bseq,
                                               unsigned* __restrict__ hdr,
                                               int* __restrict__ tok,
                                               int* __restrict__ inv) {
  const int tid = threadIdx.x;
  const int lane = tid & 63, wid = tid >> 6;
  __shared__ unsigned wsum[16][4];
  int bl[16];
  unsigned c[4] = {0, 0, 0, 0};
  const int tb = tid * 16;
#pragma unroll
  for (int i = 0; i < 16; i += 4) {
    int4 v = *(const int4*)(bseq + tb + i);
    bl[i] = v.x; bl[i + 1] = v.y; bl[i + 2] = v.z; bl[i + 3] = v.w;
  }
#pragma unroll
  for (int i = 0; i < 16; i++)
    if (bl[i] > 0) c[bl[i] - 1]++;
  unsigned inc[4];
#pragma unroll
  for (int b = 0; b < 4; b++) {
    unsigned s = c[b];
    for (int off = 1; off < 64; off <<= 1) {
      unsigned o = __shfl_up(s, off, 64);
      if (lane >= off) s += o;
    }
    inc[b] = s;
  }
  if (lane == 63)
    for (int b = 0; b < 4; b++) wsum[wid][b] = inc[b];
  __syncthreads();
  unsigned wpre[4] = {0, 0, 0, 0}, tot[4] = {0, 0, 0, 0};
  for (int w = 0; w < 16; w++)
    for (int b = 0; b < 4; b++) {
      unsigned v = wsum[w][b];
      if (w < wid) wpre[b] += v;
      tot[b] += v;
    }
  unsigned segoff[4], segpad[4], o = 0;
  for (int b = 0; b < 4; b++) {
    segoff[b] = o;
    segpad[b] = (tot[b] + 127u) & ~127u;
    o += segpad[b];
  }
  if (tid == 0) {
    for (int b = 0; b < 4; b++) {
      hdr[b] = tot[b]; hdr[4 + b] = segoff[b]; hdr[8 + b] = segpad[b];
    }
    hdr[12] = o;
  }
  unsigned pos[4];
  for (int b = 0; b < 4; b++) pos[b] = segoff[b] + wpre[b] + inc[b] - c[b];
#pragma unroll
  for (int i = 0; i < 16; i++) {
    int b = bl[i], t = tb + i;
    if (b > 0) { unsigned p = pos[b - 1]++; tok[p] = t; inv[t] = (int)p; }
    else inv[t] = -1;
  }
  for (int idx = tid; idx < 4 * 128; idx += 1024) {
    int b = idx >> 7;
    unsigned j = idx & 127u;
    if (j < segpad[b] - tot[b]) tok[segoff[b] + tot[b] + j] = -1;
  }
}

// fp32 -> bf16 bulk convert, both weight tensors in one launch.
__global__ void k_cvt2(const float* __restrict__ s1, unsigned short* __restrict__ d1,
                       const float* __restrict__ s2, unsigned short* __restrict__ d2,
                       int n) {  // n = elements per tensor (equal sizes)
  int i = (blockIdx.x * blockDim.x + threadIdx.x) * 4;
  int st = gridDim.x * blockDim.x * 4;
  for (; i < n; i += st) {
    float4 v = *(const float4*)(s1 + i);
    u16x4 o = {f2bf(v.x), f2bf(v.y), f2bf(v.z), f2bf(v.w)};
    *(u16x4*)(d1 + i) = o;
    float4 w = *(const float4*)(s2 + i);
    u16x4 p = {f2bf(w.x), f2bf(w.y), f2bf(w.z), f2bf(w.w)};
    *(u16x4*)(d2 + i) = p;
  }
}

// Gather x rows into compacted bf16 matrix xg[row][512]; zero tail pad rows.
__global__ void k_gather(const float* __restrict__ x, const int* __restrict__ tok,
                         const unsigned* __restrict__ hdr, unsigned short* __restrict__ xg) {
  const int wid = threadIdx.x >> 6, lane = threadIdx.x & 63;
  const int s = blockIdx.x * 4 + wid;
  if (s >= (int)hdr[12]) return;
  const int t = tok[s];
  u16x8 v;
  if (t >= 0) {
    const float4* xp = (const float4*)(x + (size_t)t * DM + lane * 8);
    float4 a = xp[0], b2 = xp[1];
    v[0] = f2bf(a.x); v[1] = f2bf(a.y); v[2] = f2bf(a.z); v[3] = f2bf(a.w);
    v[4] = f2bf(b2.x); v[5] = f2bf(b2.y); v[6] = f2bf(b2.z); v[7] = f2bf(b2.w);
  } else {
    for (int i = 0; i < 8; i++) v[i] = 0;
  }
  *(u16x8*)(xg + (size_t)s * DM + lane * 8) = v;
}

// ---------------------------------------------------------------------------
// Grouped GEMM, dense row-tile grid, 128x128 tile, BK=64 (round-12 core):
//   Out[row, col] (bf16) = A[row, ks*Klen .. +Klen] . W[beh][col, same]^T
// blockIdx.x = GLOBAL compacted row-tile g (rowbase = g*128); behavior is
// derived from hdr segment bounds. blockIdx.y = nt; blockIdx.z = ks.
// 256 threads = 4 waves in 2x2; per-wave 64x64 out = 4x4 16x16x32 bf16
// MFMA fragments, 32 MFMA per K-tile (2 ksegs of 16).
//
// LDS: row-major [128][64] bf16 per operand, XOR-bank-swizzled: element
// (r, k16-slot s16) lives at byte r*128 + (s16*16 ^ ((r&7)<<4)).
// STAGING (coalesced + pre-swizzled source): chunk = 8 rows; lane i covers
// row c*8 + i/8, source k-slot (i%8)^(i/8&7): each 8-lane group reads a
// contiguous 128B row segment; linear gload_lds dest realizes the swizzle
// (rule 21). READ: same XOR. Measured: 0 bank conflicts.
//
// Pipeline: 2-deep dbuf, counted vmcnt (8 loads/tile/thread), raw barriers:
//   [tile t resident] frags(kseg0) -> lgkm0 -> MFMA0 -> frags(kseg1) ->
//   lgkm0 -> barrier -> STAGE(t+2 into freed buf) -> MFMA1 ->
//   vmcnt(8|0) -> barrier.
// ---------------------------------------------------------------------------
template <int SPLITK, bool RB>
__global__ __launch_bounds__(256) void k_gemm(
    const unsigned short* __restrict__ A, const unsigned short* __restrict__ W,
    const float* __restrict__ bias, unsigned short* __restrict__ Out,
    const unsigned* __restrict__ hdr, int ldk, size_t splitStride) {
  const int Nw = gridDim.y * 128;        // output width == W rows per behavior
  const int g = blockIdx.x;              // global compacted row-tile
  const unsigned g128 = (unsigned)g * 128u;
  if (g128 >= hdr[12]) return;           // beyond total padded rows (rare)
  int beh = 0;
  while (beh < 3 && g128 >= hdr[4 + beh] + hdr[8 + beh]) beh++;
  const int nt = blockIdx.y, ks = blockIdx.z;
  const int Klen = ldk / SPLITK;
  const int rowbase = g * 128;
  const unsigned short* Ab = A + (size_t)rowbase * ldk + ks * Klen;
  const unsigned short* Wb = W + (size_t)beh * Nw * ldk + (size_t)(nt * 128) * ldk + ks * Klen;
  unsigned short* Ob = Out + (size_t)ks * splitStride;

  __shared__ unsigned short lsA[2][128 * 64];   // 2 x 16 KB
  __shared__ unsigned short lsB[2][128 * 64];   // 2 x 16 KB

  const int tid = threadIdx.x, lane = tid & 63, wid = tid >> 6;
  const int wr = wid >> 1, wc = wid & 1;

  f32x4 acc[4][4];
#pragma unroll
  for (int m = 0; m < 4; m++)
#pragma unroll
    for (int n = 0; n < 4; n++) acc[m][n] = (f32x4){0.f, 0.f, 0.f, 0.f};

  const int kq = lane >> 4, rl = lane & 15;
  const int xr = (rl & 7) << 4;            // read-side XOR (bytes)

  // staging lane decomposition
  const int sub = lane >> 3;               // row within 8-row chunk
  const int kk = ((lane & 7) ^ sub) * 8;   // pre-swizzled source k-offset (elems)

  auto STAGE = [&](int buf, int kt) {
    const int k0 = kt * 64;
#pragma unroll
    for (int j = 0; j < 4; j++) {
      const int chunk = wid * 4 + j;       // 16 chunks of 8 rows, wave-uniform
      const int r = chunk * 8 + sub;
      gload16(Ab + (size_t)r * ldk + k0 + kk, (void*)&lsA[buf][chunk * 512]);
      gload16(Wb + (size_t)r * ldk + k0 + kk, (void*)&lsB[buf][chunk * 512]);
    }
  };

  const int ntk = Klen / 64;   // 8 for both GEMMs
  STAGE(0, 0);
  STAGE(1, 1);
  asm volatile("s_waitcnt vmcnt(8)" ::: "memory");   // tile 0's 8 loads done
  __builtin_amdgcn_s_barrier();                      // tile 0 resident

  int cur = 0;
  for (int t = 0; t < ntk; ++t) {
    const char* Ac = (const char*)lsA[cur];
    const char* Bc = (const char*)lsB[cur];
    // ---- kseg 0 (k = 0..31 of this BK=64 tile) ----
    bf16x8 af[4], bfv[4];
#pragma unroll
    for (int m = 0; m < 4; m++) {
      const int r = wr * 64 + m * 16 + rl;
      af[m] = *(const bf16x8*)(Ac + r * 128 + ((kq * 16) ^ xr));
    }
#pragma unroll
    for (int n = 0; n < 4; n++) {
      const int r = wc * 64 + n * 16 + rl;
      bfv[n] = *(const bf16x8*)(Bc + r * 128 + ((kq * 16) ^ xr));
    }
    asm volatile("s_waitcnt lgkmcnt(0)" ::: "memory");
    __builtin_amdgcn_sched_barrier(0);
    __builtin_amdgcn_s_setprio(1);
#pragma unroll
    for (int m = 0; m < 4; m++)
#pragma unroll
      for (int n = 0; n < 4; n++)
        acc[m][n] = __builtin_amdgcn_mfma_f32_16x16x32_bf16(af[m], bfv[n], acc[m][n], 0, 0, 0);
    __builtin_amdgcn_s_setprio(0);
    // ---- kseg 1 (k = 32..63) ----
    bf16x8 ag[4], bgv[4];
#pragma unroll
    for (int m = 0; m < 4; m++) {
      const int r = wr * 64 + m * 16 + rl;
      ag[m] = *(const bf16x8*)(Ac + r * 128 + ((64 + kq * 16) ^ xr));
    }
#pragma unroll
    for (int n = 0; n < 4; n++) {
      const int r = wc * 64 + n * 16 + rl;
      bgv[n] = *(const bf16x8*)(Bc + r * 128 + ((64 + kq * 16) ^ xr));
    }
    asm volatile("s_waitcnt lgkmcnt(0)" ::: "memory");
    __builtin_amdgcn_sched_barrier(0);
    __builtin_amdgcn_s_barrier();        // all waves done reading buf[cur]
    if (t + 2 < ntk) STAGE(cur, t + 2);  // refill freed buffer (coalesced)
    __builtin_amdgcn_s_setprio(1);
#pragma unroll
    for (int m = 0; m < 4; m++)
#pragma unroll
      for (int n = 0; n < 4; n++)
        acc[m][n] = __builtin_amdgcn_mfma_f32_16x16x32_bf16(ag[m], bgv[n], acc[m][n], 0, 0, 0);
    __builtin_amdgcn_s_setprio(0);
    if (t + 1 < ntk) {
      if (t + 2 < ntk) asm volatile("s_waitcnt vmcnt(8)" ::: "memory");
      else             asm volatile("s_waitcnt vmcnt(0)" ::: "memory");
      __builtin_amdgcn_s_barrier();      // tile t+1 resident
    }
    cur ^= 1;
  }

  const int rj = (lane >> 4) * 4, cl = lane & 15;
#pragma unroll
  for (int n = 0; n < 4; n++) {
    const int col = nt * 128 + wc * 64 + n * 16 + cl;
    float bv = 0.f;
    if (RB) bv = bias[beh * Nw + col];
#pragma unroll
    for (int m = 0; m < 4; m++) {
      const int row0 = rowbase + wr * 64 + m * 16 + rj;
#pragma unroll
      for (int j = 0; j < 4; j++) {
        float v = acc[m][n][j] + bv;
        if (RB) v = fmaxf(v, 0.f);
        Ob[(size_t)(row0 + j) * Nw + col] = f2bf(v);
      }
    }
  }
}

// Residual + split-K partial sum + LayerNorm + gamma/beta, indexed by token
// (covers padding tokens -> zeros). One wave per token row.
__global__ void k_ln(const unsigned short* __restrict__ P, size_t splitStride,
                     const float* __restrict__ x,
                     const float* __restrict__ b2, const float* __restrict__ gamma,
                     const float* __restrict__ beta, const int* __restrict__ bseq,
                     const int* __restrict__ inv, float* __restrict__ out) {
  const int wid = threadIdx.x >> 6, lane = threadIdx.x & 63;
  const int t = blockIdx.x * 4 + wid;
  const int d0 = lane * 8;
  float4* op = (float4*)(out + (size_t)t * DM + d0);
  const int b = bseq[t];
  if (b == 0) {
    op[0] = make_float4(0.f, 0.f, 0.f, 0.f);
    op[1] = make_float4(0.f, 0.f, 0.f, 0.f);
    return;
  }
  const int beh = b - 1;
  const int s = inv[t];
  const float4* xp = (const float4*)(x + (size_t)t * DM + d0);
  float4 xa = xp[0], xb = xp[1];
  u16x8 y0 = *(const u16x8*)(P + (size_t)s * DM + d0);
  u16x8 y1 = *(const u16x8*)(P + splitStride + (size_t)s * DM + d0);
  const float* b2p = b2 + beh * DM + d0;
  float r[8];
  r[0] = xa.x + bf2f(y0[0]) + bf2f(y1[0]) + b2p[0];
  r[1] = xa.y + bf2f(y0[1]) + bf2f(y1[1]) + b2p[1];
  r[2] = xa.z + bf2f(y0[2]) + bf2f(y1[2]) + b2p[2];
  r[3] = xa.w + bf2f(y0[3]) + bf2f(y1[3]) + b2p[3];
  r[4] = xb.x + bf2f(y0[4]) + bf2f(y1[4]) + b2p[4];
  r[5] = xb.y + bf2f(y0[5]) + bf2f(y1[5]) + b2p[5];
  r[6] = xb.z + bf2f(y0[6]) + bf2f(y1[6]) + b2p[6];
  r[7] = xb.w + bf2f(y0[7]) + bf2f(y1[7]) + b2p[7];
  float sum = 0.f, sq = 0.f;
#pragma unroll
  for (int i = 0; i < 8; i++) { sum += r[i]; sq += r[i] * r[i]; }
  for (int off = 32; off; off >>= 1) {
    sum += __shfl_xor(sum, off, 64);
    sq += __shfl_xor(sq, off, 64);
  }
  const float mu = sum * (1.f / 512.f);
  const float var = sq * (1.f / 512.f) - mu * mu;
  const float rs = rsqrtf(var + 1e-5f);
  const float* gp = gamma + beh * DM + d0;
  const float* bp = beta + beh * DM + d0;
  float oo[8];
#pragma unroll
  for (int i = 0; i < 8; i++) oo[i] = (r[i] - mu) * rs * gp[i] + bp[i];
  op[0] = make_float4(oo[0], oo[1], oo[2], oo[3]);
  op[1] = make_float4(oo[4], oo[5], oo[6], oo[7]);
}

extern "C" void kernel_launch(void* const* d_in, const int* in_sizes, int n_in,
                              void* d_out, int out_size, void* d_ws, size_t ws_size,
                              hipStream_t stream) {
  const float* x     = (const float*)d_in[0];
  const int*   bseq  = (const int*)d_in[1];
  const float* W1    = (const float*)d_in[2];
  const float* b1    = (const float*)d_in[3];
  const float* W2    = (const float*)d_in[4];
  const float* b2    = (const float*)d_in[5];
  const float* gamma = (const float*)d_in[6];
  const float* beta  = (const float*)d_in[7];
  float* out = (float*)d_out;
  char* ws = (char*)d_ws;

  const size_t splitStride = (size_t)MAXR * DM;  // elements per split-K slice

  size_t off = 1024;
  unsigned* hdr = (unsigned*)ws;
  int* tok = (int*)(ws + off);                       off += (size_t)MAXR * 4;
  int* inv = (int*)(ws + off);                       off += (size_t)NTOK * 4;
  off = (off + 1023) & ~(size_t)1023;
  unsigned short* w1b = (unsigned short*)(ws + off); off += (size_t)NB * DF * DM * 2;
  unsigned short* w2b = (unsigned short*)(ws + off); off += (size_t)NB * DM * DF * 2;
  unsigned short* H   = (unsigned short*)(ws + off); off += (size_t)MAXR * DF * 2;
  // xg (GEMM1 input) and the split-K partial buffer alias: xg is dead once
  // GEMM1 completes, partials are written by GEMM2 afterwards.
  unsigned short* xg  = (unsigned short*)(ws + off);
  unsigned short* P   = (unsigned short*)(ws + off); off += 2 * splitStride * 2;
  // peak ws ~137 MB (unchanged from rounds 6-12, which passed)

  k_scan<<<1, 1024, 0, stream>>>(bseq, hdr, tok, inv);
  k_cvt2<<<1024, 256, 0, stream>>>(W1, w1b, W2, w2b, NB * DF * DM);
  k_gather<<<(MAXR + 3) / 4, 256, 0, stream>>>(x, tok, hdr, xg);
  k_gemm<1, true><<<dim3(MAXRT, DF / 128, 1), 256, 0, stream>>>(
      xg, w1b, b1, H, hdr, DM, 0);
  k_gemm<2, false><<<dim3(MAXRT, DM / 128, 2), 256, 0, stream>>>(
      H, w2b, nullptr, P, hdr, DF, splitStride);
  k_ln<<<(NTOK + 3) / 4, 256, 0, stream>>>(P, splitStride, x, b2, gamma, beta, bseq, inv, out);
}

// Round 15
// 131.650 us; speedup vs baseline: 1.0875x; 1.0875x over previous
//
#include <hip/hip_runtime.h>
#include <hip/hip_bf16.h>

// BehaviorSpecificPFF: grouped-GEMM implementation, round 15.
// r14 (B-direct-from-global) failed correctness twice-adjacent territory;
// reverted. This round = round 12 verbatim (best measured, 133us) plus one
// zero-risk fusion: k_cvt2 + k_gather merged into a single block-range-
// partitioned launch (k_prep). GEMM core: BK=64 128x128, coalesced +
// XOR-swizzled staging, 2-deep dbuf, counted vmcnt, raw barriers,
// 0 bank conflicts, sparse per-behavior grid (locality-verified vs r13).

#define NTOK 16384   // B*T = 8*2048
#define DM   512     // d_model
#define DF   2048    // d_ff
#define NB   4       // behaviors (excluding padding class 0)
#define MAXR (NTOK + 512)
#define GATB 4224    // gather blocks = (MAXR+3)/4
#define CVTB 1024    // convert blocks

typedef __attribute__((ext_vector_type(8))) short bf16x8;
typedef __attribute__((ext_vector_type(4))) float f32x4;
typedef __attribute__((ext_vector_type(4))) unsigned short u16x4;
typedef __attribute__((ext_vector_type(8))) unsigned short u16x8;

__device__ inline unsigned short f2bf(float f) {
  union { float f; unsigned u; } x; x.f = f;
  unsigned r = x.u + 0x7fffu + ((x.u >> 16) & 1u);   // RNE
  return (unsigned short)(r >> 16);
}
__device__ inline float bf2f(unsigned short h) {
  union { unsigned u; float f; } x; x.u = ((unsigned)h) << 16; return x.f;
}
__device__ inline void gload16(const void* g, void* l) {
  __builtin_amdgcn_global_load_lds(
      (const __attribute__((address_space(1))) unsigned int*)g,
      (__attribute__((address_space(3))) unsigned int*)l, 16, 0, 0);
}

// ---------------------------------------------------------------------------
// Header layout in ws (uint32): [0..3]=cnt[4], [4..7]=segoff[4] (row offsets,
// 128-aligned segments), [8..11]=segpad[4], [12]=total_padded
// ---------------------------------------------------------------------------

// Single-block ordered compaction: 1024 threads x 16 tokens each.
__global__ __launch_bounds__(1024) void k_scan(const int* __restrict__ bseq,
                                               unsigned* __restrict__ hdr,
                                               int* __restrict__ tok,
                                               int* __restrict__ inv) {
  const int tid = threadIdx.x;
  const int lane = tid & 63, wid = tid >> 6;
  __shared__ unsigned wsum[16][4];
  int bl[16];
  unsigned c[4] = {0, 0, 0, 0};
  const int tb = tid * 16;
#pragma unroll
  for (int i = 0; i < 16; i += 4) {
    int4 v = *(const int4*)(bseq + tb + i);
    bl[i] = v.x; bl[i + 1] = v.y; bl[i + 2] = v.z; bl[i + 3] = v.w;
  }
#pragma unroll
  for (int i = 0; i < 16; i++)
    if (bl[i] > 0) c[bl[i] - 1]++;
  unsigned inc[4];
#pragma unroll
  for (int b = 0; b < 4; b++) {
    unsigned s = c[b];
    for (int off = 1; off < 64; off <<= 1) {
      unsigned o = __shfl_up(s, off, 64);
      if (lane >= off) s += o;
    }
    inc[b] = s;
  }
  if (lane == 63)
    for (int b = 0; b < 4; b++) wsum[wid][b] = inc[b];
  __syncthreads();
  unsigned wpre[4] = {0, 0, 0, 0}, tot[4] = {0, 0, 0, 0};
  for (int w = 0; w < 16; w++)
    for (int b = 0; b < 4; b++) {
      unsigned v = wsum[w][b];
      if (w < wid) wpre[b] += v;
      tot[b] += v;
    }
  unsigned segoff[4], segpad[4], o = 0;
  for (int b = 0; b < 4; b++) {
    segoff[b] = o;
    segpad[b] = (tot[b] + 127u) & ~127u;
    o += segpad[b];
  }
  if (tid == 0) {
    for (int b = 0; b < 4; b++) {
      hdr[b] = tot[b]; hdr[4 + b] = segoff[b]; hdr[8 + b] = segpad[b];
    }
    hdr[12] = o;
  }
  unsigned pos[4];
  for (int b = 0; b < 4; b++) pos[b] = segoff[b] + wpre[b] + inc[b] - c[b];
#pragma unroll
  for (int i = 0; i < 16; i++) {
    int b = bl[i], t = tb + i;
    if (b > 0) { unsigned p = pos[b - 1]++; tok[p] = t; inv[t] = (int)p; }
    else inv[t] = -1;
  }
  for (int idx = tid; idx < 4 * 128; idx += 1024) {
    int b = idx >> 7;
    unsigned j = idx & 127u;
    if (j < segpad[b] - tot[b]) tok[segoff[b] + tot[b] + j] = -1;
  }
}

// Fused prep: blocks [0,GATB) gather x rows into compacted bf16 xg;
// blocks [GATB,GATB+CVTB) convert W1/W2 fp32 -> bf16 (grid-stride).
__global__ void k_prep(const float* __restrict__ x, const int* __restrict__ tok,
                       const unsigned* __restrict__ hdr, unsigned short* __restrict__ xg,
                       const float* __restrict__ W1, unsigned short* __restrict__ w1b,
                       const float* __restrict__ W2, unsigned short* __restrict__ w2b,
                       int nw) {
  if (blockIdx.x < GATB) {
    const int wid = threadIdx.x >> 6, lane = threadIdx.x & 63;
    const int s = blockIdx.x * 4 + wid;
    if (s >= (int)hdr[12]) return;
    const int t = tok[s];
    u16x8 v;
    if (t >= 0) {
      const float4* xp = (const float4*)(x + (size_t)t * DM + lane * 8);
      float4 a = xp[0], b2 = xp[1];
      v[0] = f2bf(a.x); v[1] = f2bf(a.y); v[2] = f2bf(a.z); v[3] = f2bf(a.w);
      v[4] = f2bf(b2.x); v[5] = f2bf(b2.y); v[6] = f2bf(b2.z); v[7] = f2bf(b2.w);
    } else {
      for (int i = 0; i < 8; i++) v[i] = 0;
    }
    *(u16x8*)(xg + (size_t)s * DM + lane * 8) = v;
  } else {
    int i = ((blockIdx.x - GATB) * blockDim.x + threadIdx.x) * 4;
    const int st = CVTB * blockDim.x * 4;
    for (; i < nw; i += st) {
      float4 v = *(const float4*)(W1 + i);
      u16x4 o = {f2bf(v.x), f2bf(v.y), f2bf(v.z), f2bf(v.w)};
      *(u16x4*)(w1b + i) = o;
      float4 w = *(const float4*)(W2 + i);
      u16x4 p = {f2bf(w.x), f2bf(w.y), f2bf(w.z), f2bf(w.w)};
      *(u16x4*)(w2b + i) = p;
    }
  }
}

// ---------------------------------------------------------------------------
// Grouped GEMM with optional split-K, 128x128 tile, BK=64 (round-12 core):
//   Out[row, col] (bf16) = A[row, ks*Klen .. +Klen] . W[beh][col, same]^T
// 256 threads = 4 waves in 2x2; per-wave 64x64 out = 4x4 16x16x32 bf16
// MFMA fragments, 32 MFMA per K-tile (2 ksegs of 16).
//
// LDS: row-major [128][64] bf16 per operand, XOR-bank-swizzled: element
// (r, k16-slot s16) lives at byte r*128 + (s16*16 ^ ((r&7)<<4)).
// STAGING (coalesced + pre-swizzled source): chunk = 8 rows; lane i of a
// gload16 covers row c*8 + i/8, source k-slot (i%8)^(i/8&7), so each 8-lane
// group reads a contiguous 128B row segment (full cache lines) and the
// linear LDS dest realizes the swizzle (both-sides-or-neither, rule 21).
// READ: same XOR on the ds_read address. Measured: 0 bank conflicts.
//
// Pipeline: 2-deep dbuf, counted vmcnt (8 loads/tile/thread), raw barriers:
//   [tile t resident] frags(kseg0) -> lgkm0 -> MFMA0 -> frags(kseg1) ->
//   lgkm0 -> barrier -> STAGE(t+2 into freed buf) -> MFMA1 ->
//   vmcnt(8|0) -> barrier.
// ---------------------------------------------------------------------------
template <int SPLITK, bool RB>
__global__ __launch_bounds__(256) void k_gemm(
    const unsigned short* __restrict__ A, const unsigned short* __restrict__ W,
    const float* __restrict__ bias, unsigned short* __restrict__ Out,
    const unsigned* __restrict__ hdr, int ldk, size_t splitStride) {
  const int Nw = gridDim.y * 128;        // output width == W rows per behavior
  const int rt = blockIdx.x, nt = blockIdx.y;
  const int beh = blockIdx.z / SPLITK, ks = blockIdx.z % SPLITK;
  const unsigned rows_padded = hdr[8 + beh];
  if ((unsigned)(rt * 128) >= rows_padded) return;
  const int Klen = ldk / SPLITK;
  const int rowbase = (int)hdr[4 + beh] + rt * 128;
  const unsigned short* Ab = A + (size_t)rowbase * ldk + ks * Klen;
  const unsigned short* Wb = W + (size_t)beh * Nw * ldk + (size_t)(nt * 128) * ldk + ks * Klen;
  unsigned short* Ob = Out + (size_t)ks * splitStride;

  __shared__ unsigned short lsA[2][128 * 64];   // 2 x 16 KB
  __shared__ unsigned short lsB[2][128 * 64];   // 2 x 16 KB

  const int tid = threadIdx.x, lane = tid & 63, wid = tid >> 6;
  const int wr = wid >> 1, wc = wid & 1;

  f32x4 acc[4][4];
#pragma unroll
  for (int m = 0; m < 4; m++)
#pragma unroll
    for (int n = 0; n < 4; n++) acc[m][n] = (f32x4){0.f, 0.f, 0.f, 0.f};

  const int kq = lane >> 4, rl = lane & 15;
  const int xr = (rl & 7) << 4;            // read-side XOR (bytes)

  // staging lane decomposition
  const int sub = lane >> 3;               // row within 8-row chunk
  const int kk = ((lane & 7) ^ sub) * 8;   // pre-swizzled source k-offset (elems)

  auto STAGE = [&](int buf, int kt) {
    const int k0 = kt * 64;
#pragma unroll
    for (int j = 0; j < 4; j++) {
      const int chunk = wid * 4 + j;       // 16 chunks of 8 rows, wave-uniform
      const int r = chunk * 8 + sub;
      gload16(Ab + (size_t)r * ldk + k0 + kk, (void*)&lsA[buf][chunk * 512]);
      gload16(Wb + (size_t)r * ldk + k0 + kk, (void*)&lsB[buf][chunk * 512]);
    }
  };

  const int ntk = Klen / 64;   // 8 (GEMM1) / 16 (GEMM2 split-K 2)
  STAGE(0, 0);
  STAGE(1, 1);
  asm volatile("s_waitcnt vmcnt(8)" ::: "memory");   // tile 0's 8 loads done
  __builtin_amdgcn_s_barrier();                      // tile 0 resident

  int cur = 0;
  for (int t = 0; t < ntk; ++t) {
    const char* Ac = (const char*)lsA[cur];
    const char* Bc = (const char*)lsB[cur];
    // ---- kseg 0 (k = 0..31 of this BK=64 tile) ----
    bf16x8 af[4], bfv[4];
#pragma unroll
    for (int m = 0; m < 4; m++) {
      const int r = wr * 64 + m * 16 + rl;
      af[m] = *(const bf16x8*)(Ac + r * 128 + ((kq * 16) ^ xr));
    }
#pragma unroll
    for (int n = 0; n < 4; n++) {
      const int r = wc * 64 + n * 16 + rl;
      bfv[n] = *(const bf16x8*)(Bc + r * 128 + ((kq * 16) ^ xr));
    }
    asm volatile("s_waitcnt lgkmcnt(0)" ::: "memory");
    __builtin_amdgcn_sched_barrier(0);
    __builtin_amdgcn_s_setprio(1);
#pragma unroll
    for (int m = 0; m < 4; m++)
#pragma unroll
      for (int n = 0; n < 4; n++)
        acc[m][n] = __builtin_amdgcn_mfma_f32_16x16x32_bf16(af[m], bfv[n], acc[m][n], 0, 0, 0);
    __builtin_amdgcn_s_setprio(0);
    // ---- kseg 1 (k = 32..63) ----
    bf16x8 ag[4], bgv[4];
#pragma unroll
    for (int m = 0; m < 4; m++) {
      const int r = wr * 64 + m * 16 + rl;
      ag[m] = *(const bf16x8*)(Ac + r * 128 + ((64 + kq * 16) ^ xr));
    }
#pragma unroll
    for (int n = 0; n < 4; n++) {
      const int r = wc * 64 + n * 16 + rl;
      bgv[n] = *(const bf16x8*)(Bc + r * 128 + ((64 + kq * 16) ^ xr));
    }
    asm volatile("s_waitcnt lgkmcnt(0)" ::: "memory");
    __builtin_amdgcn_sched_barrier(0);
    __builtin_amdgcn_s_barrier();        // all waves done reading buf[cur]
    if (t + 2 < ntk) STAGE(cur, t + 2);  // refill freed buffer (coalesced)
    __builtin_amdgcn_s_setprio(1);
#pragma unroll
    for (int m = 0; m < 4; m++)
#pragma unroll
      for (int n = 0; n < 4; n++)
        acc[m][n] = __builtin_amdgcn_mfma_f32_16x16x32_bf16(ag[m], bgv[n], acc[m][n], 0, 0, 0);
    __builtin_amdgcn_s_setprio(0);
    if (t + 1 < ntk) {
      if (t + 2 < ntk) asm volatile("s_waitcnt vmcnt(8)" ::: "memory");
      else             asm volatile("s_waitcnt vmcnt(0)" ::: "memory");
      __builtin_amdgcn_s_barrier();      // tile t+1 resident
    }
    cur ^= 1;
  }

  const int rj = (lane >> 4) * 4, cl = lane & 15;
#pragma unroll
  for (int n = 0; n < 4; n++) {
    const int col = nt * 128 + wc * 64 + n * 16 + cl;
    float bv = 0.f;
    if (RB) bv = bias[beh * Nw + col];
#pragma unroll
    for (int m = 0; m < 4; m++) {
      const int row0 = rowbase + wr * 64 + m * 16 + rj;
#pragma unroll
      for (int j = 0; j < 4; j++) {
        float v = acc[m][n][j] + bv;
        if (RB) v = fmaxf(v, 0.f);
        Ob[(size_t)(row0 + j) * Nw + col] = f2bf(v);
      }
    }
  }
}

// Residual + split-K partial sum + LayerNorm + gamma/beta, indexed by token
// (covers padding tokens -> zeros). One wave per token row.
__global__ void k_ln(const unsigned short* __restrict__ P, size_t splitStride,
                     const float* __restrict__ x,
                     const float* __restrict__ b2, const float* __restrict__ gamma,
                     const float* __restrict__ beta, const int* __restrict__ bseq,
                     const int* __restrict__ inv, float* __restrict__ out) {
  const int wid = threadIdx.x >> 6, lane = threadIdx.x & 63;
  const int t = blockIdx.x * 4 + wid;
  const int d0 = lane * 8;
  float4* op = (float4*)(out + (size_t)t * DM + d0);
  const int b = bseq[t];
  if (b == 0) {
    op[0] = make_float4(0.f, 0.f, 0.f, 0.f);
    op[1] = make_float4(0.f, 0.f, 0.f, 0.f);
    return;
  }
  const int beh = b - 1;
  const int s = inv[t];
  const float4* xp = (const float4*)(x + (size_t)t * DM + d0);
  float4 xa = xp[0], xb = xp[1];
  u16x8 y0 = *(const u16x8*)(P + (size_t)s * DM + d0);
  u16x8 y1 = *(const u16x8*)(P + splitStride + (size_t)s * DM + d0);
  const float* b2p = b2 + beh * DM + d0;
  float r[8];
  r[0] = xa.x + bf2f(y0[0]) + bf2f(y1[0]) + b2p[0];
  r[1] = xa.y + bf2f(y0[1]) + bf2f(y1[1]) + b2p[1];
  r[2] = xa.z + bf2f(y0[2]) + bf2f(y1[2]) + b2p[2];
  r[3] = xa.w + bf2f(y0[3]) + bf2f(y1[3]) + b2p[3];
  r[4] = xb.x + bf2f(y0[4]) + bf2f(y1[4]) + b2p[4];
  r[5] = xb.y + bf2f(y0[5]) + bf2f(y1[5]) + b2p[5];
  r[6] = xb.z + bf2f(y0[6]) + bf2f(y1[6]) + b2p[6];
  r[7] = xb.w + bf2f(y0[7]) + bf2f(y1[7]) + b2p[7];
  float sum = 0.f, sq = 0.f;
#pragma unroll
  for (int i = 0; i < 8; i++) { sum += r[i]; sq += r[i] * r[i]; }
  for (int off = 32; off; off >>= 1) {
    sum += __shfl_xor(sum, off, 64);
    sq += __shfl_xor(sq, off, 64);
  }
  const float mu = sum * (1.f / 512.f);
  const float var = sq * (1.f / 512.f) - mu * mu;
  const float rs = rsqrtf(var + 1e-5f);
  const float* gp = gamma + beh * DM + d0;
  const float* bp = beta + beh * DM + d0;
  float oo[8];
#pragma unroll
  for (int i = 0; i < 8; i++) oo[i] = (r[i] - mu) * rs * gp[i] + bp[i];
  op[0] = make_float4(oo[0], oo[1], oo[2], oo[3]);
  op[1] = make_float4(oo[4], oo[5], oo[6], oo[7]);
}

extern "C" void kernel_launch(void* const* d_in, const int* in_sizes, int n_in,
                              void* d_out, int out_size, void* d_ws, size_t ws_size,
                              hipStream_t stream) {
  const float* x     = (const float*)d_in[0];
  const int*   bseq  = (const int*)d_in[1];
  const float* W1    = (const float*)d_in[2];
  const float* b1    = (const float*)d_in[3];
  const float* W2    = (const float*)d_in[4];
  const float* b2    = (const float*)d_in[5];
  const float* gamma = (const float*)d_in[6];
  const float* beta  = (const float*)d_in[7];
  float* out = (float*)d_out;
  char* ws = (char*)d_ws;

  const size_t splitStride = (size_t)MAXR * DM;  // elements per split-K slice

  size_t off = 1024;
  unsigned* hdr = (unsigned*)ws;
  int* tok = (int*)(ws + off);                       off += (size_t)MAXR * 4;
  int* inv = (int*)(ws + off);                       off += (size_t)NTOK * 4;
  off = (off + 1023) & ~(size_t)1023;
  unsigned short* w1b = (unsigned short*)(ws + off); off += (size_t)NB * DF * DM * 2;
  unsigned short* w2b = (unsigned short*)(ws + off); off += (size_t)NB * DM * DF * 2;
  unsigned short* H   = (unsigned short*)(ws + off); off += (size_t)MAXR * DF * 2;
  // xg (GEMM1 input) and the split-K partial buffer alias: xg is dead once
  // GEMM1 completes, partials are written by GEMM2 afterwards.
  unsigned short* xg  = (unsigned short*)(ws + off);
  unsigned short* P   = (unsigned short*)(ws + off); off += 2 * splitStride * 2;
  // peak ws ~137 MB (unchanged from rounds 6-13, which passed)

  k_scan<<<1, 1024, 0, stream>>>(bseq, hdr, tok, inv);
  k_prep<<<GATB + CVTB, 256, 0, stream>>>(x, tok, hdr, xg, W1, w1b, W2, w2b,
                                          NB * DF * DM);
  k_gemm<1, true><<<dim3(NTOK / 128, DF / 128, NB), 256, 0, stream>>>(
      xg, w1b, b1, H, hdr, DM, 0);
  k_gemm<2, false><<<dim3(NTOK / 128, DM / 128, NB * 2), 256, 0, stream>>>(
      H, w2b, nullptr, P, hdr, DF, splitStride);
  k_ln<<<(NTOK + 3) / 4, 256, 0, stream>>>(P, splitStride, x, b2, gamma, beta, bseq, inv, out);
}